// Round 1
// baseline (116.944 us; speedup 1.0000x reference)
//
#include <hip/hip_runtime.h>

// ---------------------------------------------------------------------------
// FlashCausalSelfAttention (B=2, T=2048, C=1024, H=16, Hkv=4, D=64, W=512)
// Pipeline: cvt x->bf16 | transpose W->bf16 | GEMM qkv | rope | flash attn |
//           GEMM out-proj.  All MFMA bf16 16x16x32, fp32 accum.
// ---------------------------------------------------------------------------

using bf16x8 = __attribute__((ext_vector_type(8))) short;
using f32x4  = __attribute__((ext_vector_type(4))) float;

#define B_   2
#define T_   2048
#define C_   1024
#define H_   16
#define HKV_ 4
#define D_   64
#define WIN_ 512

__device__ __forceinline__ unsigned short f2b(float f) {
  union { float f; unsigned u; } v; v.f = f;
  unsigned r = v.u + 0x7FFFu + ((v.u >> 16) & 1u);   // RNE
  return (unsigned short)(r >> 16);
}
__device__ __forceinline__ float b2f(unsigned short h) {
  union { unsigned u; float f; } v; v.u = ((unsigned)h) << 16; return v.f;
}

typedef const __attribute__((address_space(1))) void* gas_ptr;
typedef __attribute__((address_space(3))) void* las_ptr;
__device__ __forceinline__ void gl_lds16(const void* g, void* l) {
  __builtin_amdgcn_global_load_lds((gas_ptr)g, (las_ptr)l, 16, 0, 0);
}

// ---------------------------------------------------------------- prep ----
__global__ __launch_bounds__(256) void cvt_kernel(const float* __restrict__ X,
                                                  unsigned short* __restrict__ Y,
                                                  int n4) {
  int i = blockIdx.x * 256 + threadIdx.x;
  if (i >= n4) return;
  float4 v = ((const float4*)X)[i];
  ushort4 o; o.x = f2b(v.x); o.y = f2b(v.y); o.z = f2b(v.z); o.w = f2b(v.w);
  ((ushort4*)Y)[i] = o;
}

// W (K x N) fp32  ->  WT (N x K) bf16
__global__ __launch_bounds__(256) void transpose_cvt(const float* __restrict__ W,
                                                     unsigned short* __restrict__ WT,
                                                     int K, int N) {
  __shared__ float tile[32][33];
  int n0 = blockIdx.x * 32, k0 = blockIdx.y * 32;
  int tx = threadIdx.x & 31, ty = threadIdx.x >> 5;   // 32 x 8
#pragma unroll
  for (int yy = 0; yy < 32; yy += 8)
    tile[ty + yy][tx] = W[(size_t)(k0 + ty + yy) * N + n0 + tx];
  __syncthreads();
#pragma unroll
  for (int yy = 0; yy < 32; yy += 8)
    WT[(size_t)(n0 + ty + yy) * K + k0 + tx] = f2b(tile[tx][ty + yy]);
}

// ------------------------------------------------------------ QKV GEMM ----
// A: xb [4096][1024] bf16.  Bt: W^T bf16 (row = out-col n, 1024 k-cols).
// C cols: [0,1024) -> q_buf (b,h,t,d) ; [1024,1280) -> k_buf (b,hkv,t,d) ;
//         [1280,1536) -> v_bufT (b,hkv,d,t)
__global__ __launch_bounds__(256) void gemm_qkv(
    const unsigned short* __restrict__ A,
    const unsigned short* __restrict__ WqT,
    const unsigned short* __restrict__ WkT,
    const unsigned short* __restrict__ WvT,
    unsigned short* __restrict__ qb,
    unsigned short* __restrict__ kbuf,
    unsigned short* __restrict__ vbT) {
  const int K = 1024;
  __shared__ unsigned short lA[128 * 32];
  __shared__ unsigned short lB[128 * 32];
  int tid = threadIdx.x, l = tid & 63, w = tid >> 6;
  int wr = w >> 1, wc = w & 1;
  int m0 = blockIdx.x * 128;
  int n0 = blockIdx.y * 128;
  const unsigned short* Bt; int nloc;
  if (n0 < 1024)      { Bt = WqT; nloc = n0; }
  else if (n0 < 1280) { Bt = WkT; nloc = n0 - 1024; }
  else                { Bt = WvT; nloc = n0 - 1280; }

  f32x4 acc[4][4] = {};

  const unsigned short* ga = A  + (size_t)(m0   + w*16 + (l >> 2)) * K + (l & 3) * 8;
  const unsigned short* gb = Bt + (size_t)(nloc + w*16 + (l >> 2)) * K + (l & 3) * 8;
  unsigned short* la0 = &lA[(w * 16) * 32];
  unsigned short* lb0 = &lB[(w * 16) * 32];

  for (int k0 = 0; k0 < K; k0 += 32) {
    gl_lds16(ga + k0,                  la0);
    gl_lds16(ga + (size_t)64 * K + k0, la0 + 64 * 32);
    gl_lds16(gb + k0,                  lb0);
    gl_lds16(gb + (size_t)64 * K + k0, lb0 + 64 * 32);
    __syncthreads();
    bf16x8 af[4], bfr[4];
#pragma unroll
    for (int mf = 0; mf < 4; ++mf)
      af[mf] = *(const bf16x8*)(&lA[(wr * 64 + mf * 16 + (l & 15)) * 32 + (l >> 4) * 8]);
#pragma unroll
    for (int nf = 0; nf < 4; ++nf)
      bfr[nf] = *(const bf16x8*)(&lB[(wc * 64 + nf * 16 + (l & 15)) * 32 + (l >> 4) * 8]);
#pragma unroll
    for (int mf = 0; mf < 4; ++mf)
#pragma unroll
      for (int nf = 0; nf < 4; ++nf)
        acc[mf][nf] = __builtin_amdgcn_mfma_f32_16x16x32_bf16(af[mf], bfr[nf], acc[mf][nf], 0, 0, 0);
    __syncthreads();
  }

  int colbase = n0 + wc * 64;
  int rowbase = m0 + wr * 64;
#pragma unroll
  for (int mf = 0; mf < 4; ++mf)
#pragma unroll
    for (int nf = 0; nf < 4; ++nf) {
      int n    = colbase + nf * 16 + (l & 15);
      int mrow = rowbase + mf * 16 + ((l >> 4) << 2);
      int b = mrow >> 11, t = mrow & 2047;
      if (n < 1024) {                      // Q: (b,h,t,d)
        int h = n >> 6, d = n & 63;
        size_t base = ((size_t)(b * 16 + h) * 2048 + t) * 64 + d;
#pragma unroll
        for (int i = 0; i < 4; ++i) qb[base + (size_t)i * 64] = f2b(acc[mf][nf][i]);
      } else if (n < 1280) {               // K: (b,hkv,t,d)
        int hh = (n - 1024) >> 6, d = n & 63;
        size_t base = ((size_t)(b * 4 + hh) * 2048 + t) * 64 + d;
#pragma unroll
        for (int i = 0; i < 4; ++i) kbuf[base + (size_t)i * 64] = f2b(acc[mf][nf][i]);
      } else {                             // V transposed: (b,hkv,d,t)
        int hh = (n - 1280) >> 6, d = n & 63;
        size_t base = ((size_t)((b * 4 + hh) * 64 + d)) * 2048 + t;
        ushort4 pk;
        pk.x = f2b(acc[mf][nf][0]); pk.y = f2b(acc[mf][nf][1]);
        pk.z = f2b(acc[mf][nf][2]); pk.w = f2b(acc[mf][nf][3]);
        *(ushort4*)(&vbT[base]) = pk;
      }
    }
}

// ---------------------------------------------------------------- rope ----
// In-place rotate-half RoPE on q (with 1/sqrt(D) folded in) and k, bf16.
__global__ __launch_bounds__(256) void rope_kernel(unsigned short* __restrict__ qb,
                                                   unsigned short* __restrict__ kb) {
  int idx = blockIdx.x * 256 + threadIdx.x;
  const int NQ = B_ * H_ * T_ * 32;          // 2097152 pairs
  const int NT = NQ + B_ * HKV_ * T_ * 32;   // + 524288
  if (idx >= NT) return;
  unsigned short* buf; int i; float sc;
  if (idx < NQ) { buf = qb; i = idx; sc = 0.125f; }
  else          { buf = kb; i = idx - NQ; sc = 1.0f; }
  int d = i & 31;
  int t = (i >> 5) & 2047;
  int bh = i >> 16;
  size_t base = ((size_t)bh * 2048 + t) * 64;
  float x1 = b2f(buf[base + d]);
  float x2 = b2f(buf[base + d + 32]);
  // inv_freq = 10000^(-d/32) = 2^(-d*log2(1e4)/32)
  float inv = exp2f(-(float)d * (13.287712379549449f / 32.0f));
  float ang = (float)t * inv;
  float sn, cs;
  sincosf(ang, &sn, &cs);
  buf[base + d]      = f2b((x1 * cs - x2 * sn) * sc);
  buf[base + d + 32] = f2b((x2 * cs + x1 * sn) * sc);
}

// ----------------------------------------------------------- attention ----
// One block = (b, h, 64-row q-tile); 4 waves x 16 q-rows each.
// K/V staged per 64-key tile; window+causal mask; online softmax; PV via LDS P.
__global__ __launch_bounds__(256) void attn_kernel(
    const unsigned short* __restrict__ qb,
    const unsigned short* __restrict__ kb,
    const unsigned short* __restrict__ vbT,
    const int* __restrict__ seqlen,
    unsigned short* __restrict__ att) {
  __shared__ unsigned short kl[64 * 72];       // [key][dim] pad 72
  __shared__ unsigned short vt[64 * 72];       // [dim][key] pad 72
  __shared__ unsigned short pl[4][16 * 72];    // per-wave P [qrow][key]

  int bx = blockIdx.x;
  int qt = bx & 31;
  int h  = (bx >> 5) & 15;
  int b  = bx >> 9;
  int tid = threadIdx.x, l = tid & 63, w = tid >> 6;
  int q0 = qt << 6;
  int r0 = q0 + w * 16;
  int hk = h >> 2;
  int slen = seqlen[b];

  const unsigned short* qbase = qb  + ((size_t)(b * 16 + h)  * 2048) * 64;
  const unsigned short* kbase = kb  + ((size_t)(b * 4  + hk) * 2048) * 64;
  const unsigned short* vbase = vbT + ((size_t)(b * 4  + hk) * 64)   * 2048;

  bf16x8 aq[2];
#pragma unroll
  for (int s = 0; s < 2; ++s)
    aq[s] = *(const bf16x8*)(qbase + (size_t)(r0 + (l & 15)) * 64 + s * 32 + (l >> 4) * 8);

  f32x4 o[4] = {};
  float m_i[4], l_i[4];
#pragma unroll
  for (int i = 0; i < 4; ++i) { m_i[i] = -1e30f; l_i[i] = 0.f; }

  int t_lo = q0 >= WIN_ ? (q0 - WIN_) >> 6 : 0;
  for (int kt = t_lo; kt <= qt; ++kt) {
    int kb0 = kt << 6;
    __syncthreads();
#pragma unroll
    for (int it = 0; it < 4; ++it) {
      int idx = it * 256 + tid;
      int row = idx >> 4, c4 = (idx & 15) << 2;
      *(ushort4*)(&kl[row * 72 + c4]) =
          *(const ushort4*)(kbase + (size_t)(kb0 + row) * 64 + c4);
      *(ushort4*)(&vt[row * 72 + c4]) =
          *(const ushort4*)(vbase + (size_t)row * 2048 + kb0 + c4);
    }
    __syncthreads();

    f32x4 sa[4];
#pragma unroll
    for (int nf = 0; nf < 4; ++nf) {
      f32x4 z = {};
      const unsigned short* kp = &kl[(nf * 16 + (l & 15)) * 72 + (l >> 4) * 8];
      z = __builtin_amdgcn_mfma_f32_16x16x32_bf16(aq[0], *(const bf16x8*)kp,        z, 0, 0, 0);
      z = __builtin_amdgcn_mfma_f32_16x16x32_bf16(aq[1], *(const bf16x8*)(kp + 32), z, 0, 0, 0);
      sa[nf] = z;
    }

    float sv[4][4], rm[4];
#pragma unroll
    for (int i = 0; i < 4; ++i) rm[i] = -1e30f;
#pragma unroll
    for (int nf = 0; nf < 4; ++nf) {
      int key = kb0 + nf * 16 + (l & 15);
#pragma unroll
      for (int i = 0; i < 4; ++i) {
        int qr = r0 + (l >> 4) * 4 + i;
        float x = sa[nf][i];
        x = (key <= qr && key >= qr - WIN_) ? x : -1e30f;
        sv[nf][i] = x;
        rm[i] = fmaxf(rm[i], x);
      }
    }
#pragma unroll
    for (int off = 1; off <= 8; off <<= 1)
#pragma unroll
      for (int i = 0; i < 4; ++i)
        rm[i] = fmaxf(rm[i], __shfl_xor(rm[i], off));

    float corr[4], rs[4], pr[4][4];
#pragma unroll
    for (int i = 0; i < 4; ++i) {
      float mn = fmaxf(m_i[i], rm[i]);
      corr[i] = __expf(m_i[i] - mn);
      m_i[i] = mn;
      float s = 0.f;
#pragma unroll
      for (int nf = 0; nf < 4; ++nf) {
        float p = __expf(sv[nf][i] - mn);
        pr[nf][i] = p; s += p;
      }
      rs[i] = s;
    }
#pragma unroll
    for (int off = 1; off <= 8; off <<= 1)
#pragma unroll
      for (int i = 0; i < 4; ++i)
        rs[i] += __shfl_xor(rs[i], off);
#pragma unroll
    for (int i = 0; i < 4; ++i) l_i[i] = l_i[i] * corr[i] + rs[i];
#pragma unroll
    for (int df = 0; df < 4; ++df)
#pragma unroll
      for (int i = 0; i < 4; ++i) o[df][i] *= corr[i];

#pragma unroll
    for (int nf = 0; nf < 4; ++nf)
#pragma unroll
      for (int i = 0; i < 4; ++i)
        pl[w][((l >> 4) * 4 + i) * 72 + nf * 16 + (l & 15)] = f2b(pr[nf][i]);

    bf16x8 ap0 = *(const bf16x8*)(&pl[w][(l & 15) * 72 + (l >> 4) * 8]);
    bf16x8 ap1 = *(const bf16x8*)(&pl[w][(l & 15) * 72 + 32 + (l >> 4) * 8]);
#pragma unroll
    for (int df = 0; df < 4; ++df) {
      const unsigned short* vp = &vt[(df * 16 + (l & 15)) * 72 + (l >> 4) * 8];
      o[df] = __builtin_amdgcn_mfma_f32_16x16x32_bf16(ap0, *(const bf16x8*)vp,        o[df], 0, 0, 0);
      o[df] = __builtin_amdgcn_mfma_f32_16x16x32_bf16(ap1, *(const bf16x8*)(vp + 32), o[df], 0, 0, 0);
    }
  }

#pragma unroll
  for (int i = 0; i < 4; ++i) {
    int r = r0 + (l >> 4) * 4 + i;
    float inv = (r < slen && l_i[i] > 0.f) ? 1.0f / l_i[i] : 0.f;
#pragma unroll
    for (int df = 0; df < 4; ++df)
      att[((size_t)(b * 2048 + r)) * 1024 + h * 64 + df * 16 + (l & 15)] =
          f2b(o[df][i] * inv);
  }
}

// ----------------------------------------------------------- out GEMM -----
__global__ __launch_bounds__(256) void gemm_out(
    const unsigned short* __restrict__ A,    // att [4096][1024] bf16
    const unsigned short* __restrict__ Bt,   // WoT [1024][1024] bf16
    float* __restrict__ C) {
  const int K = 1024;
  __shared__ unsigned short lA[128 * 32];
  __shared__ unsigned short lB[128 * 32];
  int tid = threadIdx.x, l = tid & 63, w = tid >> 6;
  int wr = w >> 1, wc = w & 1;
  int m0 = blockIdx.x * 128;
  int n0 = blockIdx.y * 128;

  f32x4 acc[4][4] = {};

  const unsigned short* ga = A  + (size_t)(m0 + w*16 + (l >> 2)) * K + (l & 3) * 8;
  const unsigned short* gb = Bt + (size_t)(n0 + w*16 + (l >> 2)) * K + (l & 3) * 8;
  unsigned short* la0 = &lA[(w * 16) * 32];
  unsigned short* lb0 = &lB[(w * 16) * 32];

  for (int k0 = 0; k0 < K; k0 += 32) {
    gl_lds16(ga + k0,                  la0);
    gl_lds16(ga + (size_t)64 * K + k0, la0 + 64 * 32);
    gl_lds16(gb + k0,                  lb0);
    gl_lds16(gb + (size_t)64 * K + k0, lb0 + 64 * 32);
    __syncthreads();
    bf16x8 af[4], bfr[4];
#pragma unroll
    for (int mf = 0; mf < 4; ++mf)
      af[mf] = *(const bf16x8*)(&lA[(wr * 64 + mf * 16 + (l & 15)) * 32 + (l >> 4) * 8]);
#pragma unroll
    for (int nf = 0; nf < 4; ++nf)
      bfr[nf] = *(const bf16x8*)(&lB[(wc * 64 + nf * 16 + (l & 15)) * 32 + (l >> 4) * 8]);
#pragma unroll
    for (int mf = 0; mf < 4; ++mf)
#pragma unroll
      for (int nf = 0; nf < 4; ++nf)
        acc[mf][nf] = __builtin_amdgcn_mfma_f32_16x16x32_bf16(af[mf], bfr[nf], acc[mf][nf], 0, 0, 0);
    __syncthreads();
  }

  int colbase = n0 + wc * 64;
  int rowbase = m0 + wr * 64;
#pragma unroll
  for (int mf = 0; mf < 4; ++mf)
#pragma unroll
    for (int nf = 0; nf < 4; ++nf) {
      int n    = colbase + nf * 16 + (l & 15);
      int mrow = rowbase + mf * 16 + ((l >> 4) << 2);
#pragma unroll
      for (int i = 0; i < 4; ++i)
        C[(size_t)(mrow + i) * 1024 + n] = acc[mf][nf][i];
    }
}

// ---------------------------------------------------------------------------
extern "C" void kernel_launch(void* const* d_in, const int* in_sizes, int n_in,
                              void* d_out, int out_size, void* d_ws, size_t ws_size,
                              hipStream_t stream) {
  const float* x  = (const float*)d_in[0];
  const int*   sl = (const int*)d_in[1];
  const float* Wq = (const float*)d_in[2];
  const float* Wk = (const float*)d_in[3];
  const float* Wv = (const float*)d_in[4];
  const float* Wo = (const float*)d_in[5];
  float* out = (float*)d_out;

  char* p = (char*)d_ws;                       // ~33 MB total
  unsigned short* xb  = (unsigned short*)p; p += (size_t)4096 * 1024 * 2;
  unsigned short* wqT = (unsigned short*)p; p += (size_t)1024 * 1024 * 2;
  unsigned short* wkT = (unsigned short*)p; p += (size_t)256  * 1024 * 2;
  unsigned short* wvT = (unsigned short*)p; p += (size_t)256  * 1024 * 2;
  unsigned short* woT = (unsigned short*)p; p += (size_t)1024 * 1024 * 2;
  unsigned short* qb  = (unsigned short*)p; p += (size_t)B_ * H_   * T_ * D_ * 2;
  unsigned short* kbf = (unsigned short*)p; p += (size_t)B_ * HKV_ * T_ * D_ * 2;
  unsigned short* vbT = (unsigned short*)p; p += (size_t)B_ * HKV_ * D_ * T_ * 2;
  unsigned short* att = (unsigned short*)p; p += (size_t)4096 * 1024 * 2;

  cvt_kernel<<<4096, 256, 0, stream>>>(x, xb, 4096 * 1024 / 4);
  transpose_cvt<<<dim3(32, 32), 256, 0, stream>>>(Wq, wqT, 1024, 1024);
  transpose_cvt<<<dim3(8, 32),  256, 0, stream>>>(Wk, wkT, 1024, 256);
  transpose_cvt<<<dim3(8, 32),  256, 0, stream>>>(Wv, wvT, 1024, 256);
  transpose_cvt<<<dim3(32, 32), 256, 0, stream>>>(Wo, woT, 1024, 1024);
  gemm_qkv<<<dim3(32, 12), 256, 0, stream>>>(xb, wqT, wkT, wvT, qb, kbf, vbT);
  rope_kernel<<<10240, 256, 0, stream>>>(qb, kbf);
  attn_kernel<<<1024, 256, 0, stream>>>(qb, kbf, vbT, sl, att);
  gemm_out<<<dim3(32, 8), 256, 0, stream>>>(att, woT, out);
}

// Round 2
// 112.468 us; speedup vs baseline: 1.0398x; 1.0398x over previous
//
#include <hip/hip_runtime.h>

// ---------------------------------------------------------------------------
// FlashCausalSelfAttention (B=2, T=2048, C=1024, H=16, Hkv=4, D=64, W=512)
// cvt x->bf16 | fused W transposes | GEMM qkv (+fused RoPE epilogue) |
// flash attn (KVBLK=128, reg-prefetch, defer-max, exp2 domain) | GEMM out.
// ---------------------------------------------------------------------------

using bf16x8 = __attribute__((ext_vector_type(8))) short;
using f32x4  = __attribute__((ext_vector_type(4))) float;

#define B_   2
#define T_   2048
#define H_   16
#define HKV_ 4
#define D_   64
#define WIN_ 512

// log2e/8 folded into Q (exp2-domain softmax), log2(10000)/32 for inv_freq
#define QSCALE_ 0.18033688011112042f
#define LOG2_1E4_OVER32_ 0.41524101186092029f

__device__ __forceinline__ unsigned short f2b(float f) {
  union { float f; unsigned u; } v; v.f = f;
  unsigned r = v.u + 0x7FFFu + ((v.u >> 16) & 1u);   // RNE
  return (unsigned short)(r >> 16);
}
__device__ __forceinline__ unsigned short f2b_fast(float f) {
  union { float f; unsigned u; } v; v.f = f;
  return (unsigned short)((v.u + 0x8000u) >> 16);    // round-half-up
}

typedef const __attribute__((address_space(1))) void* gas_ptr;
typedef __attribute__((address_space(3))) void* las_ptr;
__device__ __forceinline__ void gl_lds16(const void* g, void* l) {
  __builtin_amdgcn_global_load_lds((gas_ptr)g, (las_ptr)l, 16, 0, 0);
}

// ---------------------------------------------------------------- prep ----
__global__ __launch_bounds__(256) void cvt_kernel(const float* __restrict__ X,
                                                  unsigned short* __restrict__ Y,
                                                  int n4) {
  int i = blockIdx.x * 256 + threadIdx.x;
  if (i >= n4) return;
  float4 v = ((const float4*)X)[i];
  ushort4 o; o.x = f2b(v.x); o.y = f2b(v.y); o.z = f2b(v.z); o.w = f2b(v.w);
  ((ushort4*)Y)[i] = o;
}

// All four W (1024 x N) fp32 -> WT (N x 1024) bf16, one launch.
__global__ __launch_bounds__(256) void transpose_all(
    const float* __restrict__ Wq, const float* __restrict__ Wk,
    const float* __restrict__ Wv, const float* __restrict__ Wo,
    unsigned short* __restrict__ wqT, unsigned short* __restrict__ wkT,
    unsigned short* __restrict__ wvT, unsigned short* __restrict__ woT) {
  __shared__ float tile[32][33];
  const float* W; unsigned short* WT; int N;
  int z = blockIdx.z;
  if (z == 0)      { W = Wq; WT = wqT; N = 1024; }
  else if (z == 1) { W = Wo; WT = woT; N = 1024; }
  else if (z == 2) { W = Wk; WT = wkT; N = 256;  }
  else             { W = Wv; WT = wvT; N = 256;  }
  int n0 = blockIdx.x * 32;
  if (n0 >= N) return;
  int k0 = blockIdx.y * 32;
  int tx = threadIdx.x & 31, ty = threadIdx.x >> 5;   // 32 x 8
#pragma unroll
  for (int yy = 0; yy < 32; yy += 8)
    tile[ty + yy][tx] = W[(size_t)(k0 + ty + yy) * N + n0 + tx];
  __syncthreads();
#pragma unroll
  for (int yy = 0; yy < 32; yy += 8)
    WT[(size_t)(n0 + ty + yy) * 1024 + k0 + tx] = f2b(tile[tx][ty + yy]);
}

// ------------------------------------------------------------ QKV GEMM ----
// C cols: [0,1024) -> q (b,h,t,d) w/ RoPE+scale ; [1024,1280) -> k w/ RoPE ;
//         [1280,1536) -> v transposed (b,hkv,d,t)
__global__ __launch_bounds__(256) void gemm_qkv(
    const unsigned short* __restrict__ A,
    const unsigned short* __restrict__ WqT,
    const unsigned short* __restrict__ WkT,
    const unsigned short* __restrict__ WvT,
    unsigned short* __restrict__ qb,
    unsigned short* __restrict__ kbuf,
    unsigned short* __restrict__ vbT) {
  const int K = 1024;
  __shared__ unsigned short lA[128 * 32];
  __shared__ unsigned short lB[128 * 32];
  int tid = threadIdx.x, l = tid & 63, w = tid >> 6;
  int wr = w >> 1, wc = w & 1;
  int m0 = blockIdx.x * 128;
  int n0 = blockIdx.y * 128;
  const unsigned short* Bt; int nloc;
  if (n0 < 1024)      { Bt = WqT; nloc = n0; }
  else if (n0 < 1280) { Bt = WkT; nloc = n0 - 1024; }
  else                { Bt = WvT; nloc = n0 - 1280; }

  f32x4 acc[4][4] = {};

  const unsigned short* ga = A  + (size_t)(m0   + w*16 + (l >> 2)) * K + (l & 3) * 8;
  const unsigned short* gb = Bt + (size_t)(nloc + w*16 + (l >> 2)) * K + (l & 3) * 8;
  unsigned short* la0 = &lA[(w * 16) * 32];
  unsigned short* lb0 = &lB[(w * 16) * 32];

  for (int k0 = 0; k0 < K; k0 += 32) {
    gl_lds16(ga + k0,                  la0);
    gl_lds16(ga + (size_t)64 * K + k0, la0 + 64 * 32);
    gl_lds16(gb + k0,                  lb0);
    gl_lds16(gb + (size_t)64 * K + k0, lb0 + 64 * 32);
    __syncthreads();
    bf16x8 af[4], bfr[4];
#pragma unroll
    for (int mf = 0; mf < 4; ++mf)
      af[mf] = *(const bf16x8*)(&lA[(wr * 64 + mf * 16 + (l & 15)) * 32 + (l >> 4) * 8]);
#pragma unroll
    for (int nf = 0; nf < 4; ++nf)
      bfr[nf] = *(const bf16x8*)(&lB[(wc * 64 + nf * 16 + (l & 15)) * 32 + (l >> 4) * 8]);
#pragma unroll
    for (int mf = 0; mf < 4; ++mf)
#pragma unroll
      for (int nf = 0; nf < 4; ++nf)
        acc[mf][nf] = __builtin_amdgcn_mfma_f32_16x16x32_bf16(af[mf], bfr[nf], acc[mf][nf], 0, 0, 0);
    __syncthreads();
  }

  int colbase = n0 + wc * 64;
  int rowbase = m0 + wr * 64;

  // --- fused RoPE on Q/K (pair d, d+32 lives in frags nf, nf+2 of this lane)
  if (n0 < 1280) {
    float qs = (n0 < 1024) ? QSCALE_ : 1.0f;
#pragma unroll
    for (int nf = 0; nf < 2; ++nf) {
      int dd = nf * 16 + (l & 15);                       // d < 32
      float inv = exp2f(-(float)dd * LOG2_1E4_OVER32_);
#pragma unroll
      for (int mf = 0; mf < 4; ++mf) {
#pragma unroll
        for (int i = 0; i < 4; ++i) {
          int t = (rowbase + mf * 16 + ((l >> 4) << 2) + i) & 2047;
          float sn, cs;
          __sincosf((float)t * inv, &sn, &cs);
          float x1 = acc[mf][nf][i], x2 = acc[mf][nf + 2][i];
          acc[mf][nf][i]     = (x1 * cs - x2 * sn) * qs;
          acc[mf][nf + 2][i] = (x2 * cs + x1 * sn) * qs;
        }
      }
    }
  }

#pragma unroll
  for (int mf = 0; mf < 4; ++mf)
#pragma unroll
    for (int nf = 0; nf < 4; ++nf) {
      int n    = colbase + nf * 16 + (l & 15);
      int mrow = rowbase + mf * 16 + ((l >> 4) << 2);
      int b = mrow >> 11, t = mrow & 2047;
      if (n < 1024) {                      // Q
        int h = n >> 6, d = n & 63;
        size_t base = ((size_t)(b * 16 + h) * 2048 + t) * 64 + d;
#pragma unroll
        for (int i = 0; i < 4; ++i) qb[base + (size_t)i * 64] = f2b(acc[mf][nf][i]);
      } else if (n < 1280) {               // K
        int hh = (n - 1024) >> 6, d = n & 63;
        size_t base = ((size_t)(b * 4 + hh) * 2048 + t) * 64 + d;
#pragma unroll
        for (int i = 0; i < 4; ++i) kbuf[base + (size_t)i * 64] = f2b(acc[mf][nf][i]);
      } else {                             // V transposed (b,hkv,d,t)
        int hh = (n - 1280) >> 6, d = n & 63;
        size_t base = ((size_t)((b * 4 + hh) * 64 + d)) * 2048 + t;
        ushort4 pk;
        pk.x = f2b(acc[mf][nf][0]); pk.y = f2b(acc[mf][nf][1]);
        pk.z = f2b(acc[mf][nf][2]); pk.w = f2b(acc[mf][nf][3]);
        *(ushort4*)(&vbT[base]) = pk;
      }
    }
}

// ----------------------------------------------------------- attention ----
// Block = (b,h,64-q-tile); 4 waves x 16 q-rows. KVBLK=128, reg-prefetch
// staging, mask-free interior tiles, exp2-domain online softmax, defer-max.
__global__ __launch_bounds__(256) void attn_kernel(
    const unsigned short* __restrict__ qb,
    const unsigned short* __restrict__ kb,
    const unsigned short* __restrict__ vbT,
    const int* __restrict__ seqlen,
    unsigned short* __restrict__ att) {
  __shared__ unsigned short kl[128 * 72];      // [key][dim]  pad 72
  __shared__ unsigned short vt[64 * 136];      // [dim][key]  pad 136
  __shared__ unsigned short pl[4][16 * 140];   // per-wave P [qrow][key] pad 140

  int bx = blockIdx.x;
  int qt = bx & 31;
  int h  = (bx >> 5) & 15;
  int b  = bx >> 9;
  int tid = threadIdx.x, l = tid & 63, w = tid >> 6;
  int q0 = qt << 6;
  int r0 = q0 + w * 16;
  int hk = h >> 2;
  int slen = seqlen[b];

  const unsigned short* qbase = qb  + ((size_t)(b * 16 + h)  * 2048) * 64;
  const unsigned short* kbase = kb  + ((size_t)(b * 4  + hk) * 2048) * 64;
  const unsigned short* vbase = vbT + ((size_t)(b * 4  + hk) * 64)   * 2048;

  bf16x8 aq[2];
#pragma unroll
  for (int s = 0; s < 2; ++s)
    aq[s] = *(const bf16x8*)(qbase + (size_t)(r0 + (l & 15)) * 64 + s * 32 + (l >> 4) * 8);

  f32x4 o[4] = {};
  float m_i[4], l_i[4];
#pragma unroll
  for (int i = 0; i < 4; ++i) { m_i[i] = -1e30f; l_i[i] = 0.f; }

  int lo = q0 >= WIN_ ? ((q0 - WIN_) >> 7) << 7 : 0;
  int hi = q0 + 63;

  ushort4 kr[8], vr[8];
#define PREFETCH(KB0)                                                          \
  {                                                                            \
    _Pragma("unroll")                                                          \
    for (int it = 0; it < 8; ++it) {                                           \
      int idx = it * 256 + tid;                                                \
      kr[it] = *(const ushort4*)(kbase + (size_t)((KB0) + (idx >> 4)) * 64 +   \
                                 ((idx & 15) << 2));                           \
      vr[it] = *(const ushort4*)(vbase + (size_t)(idx >> 5) * 2048 + (KB0) +   \
                                 ((idx & 31) << 2));                           \
    }                                                                          \
  }

  PREFETCH(lo);
  for (int kb0 = lo; kb0 <= hi; kb0 += 128) {
    __syncthreads();
#pragma unroll
    for (int it = 0; it < 8; ++it) {
      int idx = it * 256 + tid;
      *(ushort4*)(&kl[(idx >> 4) * 72 + ((idx & 15) << 2)]) = kr[it];
      *(ushort4*)(&vt[(idx >> 5) * 136 + ((idx & 31) << 2)]) = vr[it];
    }
    __syncthreads();
    if (kb0 + 128 <= hi) PREFETCH(kb0 + 128);

    // ---- QK^T (S' already in log2e units via folded Q scale)
    f32x4 sa[8];
#pragma unroll
    for (int nf = 0; nf < 8; ++nf) {
      f32x4 z = {};
      const unsigned short* kp = &kl[(nf * 16 + (l & 15)) * 72 + (l >> 4) * 8];
      z = __builtin_amdgcn_mfma_f32_16x16x32_bf16(aq[0], *(const bf16x8*)kp,        z, 0, 0, 0);
      z = __builtin_amdgcn_mfma_f32_16x16x32_bf16(aq[1], *(const bf16x8*)(kp + 32), z, 0, 0, 0);
      sa[nf] = z;
    }

    // ---- mask (only diagonal + trailing window tile need it)
    bool noMask = (kb0 + 128 <= q0) && (kb0 >= q0 - 449);
    float rm[4];
#pragma unroll
    for (int i = 0; i < 4; ++i) rm[i] = -1e30f;
    if (noMask) {
#pragma unroll
      for (int nf = 0; nf < 8; ++nf)
#pragma unroll
        for (int i = 0; i < 4; ++i) rm[i] = fmaxf(rm[i], sa[nf][i]);
    } else {
#pragma unroll
      for (int nf = 0; nf < 8; ++nf) {
        int key = kb0 + nf * 16 + (l & 15);
#pragma unroll
        for (int i = 0; i < 4; ++i) {
          int qr = r0 + (l >> 4) * 4 + i;
          float x = (key <= qr && key >= qr - WIN_) ? sa[nf][i] : -1e30f;
          sa[nf][i] = x;
          rm[i] = fmaxf(rm[i], x);
        }
      }
    }
#pragma unroll
    for (int off = 1; off <= 8; off <<= 1)
#pragma unroll
      for (int i = 0; i < 4; ++i)
        rm[i] = fmaxf(rm[i], __shfl_xor(rm[i], off));

    // ---- defer-max: skip rescale when max growth <= 8 (2^8 bounded P)
    int flag = (rm[0] - m_i[0] <= 8.f) & (rm[1] - m_i[1] <= 8.f) &
               (rm[2] - m_i[2] <= 8.f) & (rm[3] - m_i[3] <= 8.f);
    bool skip = __all(flag);

    float corr[4], rs[4];
#pragma unroll
    for (int i = 0; i < 4; ++i) {
      float mn = skip ? m_i[i] : fmaxf(m_i[i], rm[i]);
      corr[i] = skip ? 1.f : exp2f(m_i[i] - mn);
      m_i[i] = mn;
      float s = 0.f;
#pragma unroll
      for (int nf = 0; nf < 8; ++nf) {
        float p = exp2f(sa[nf][i] - mn);
        sa[nf][i] = p; s += p;
      }
      rs[i] = s;
    }
#pragma unroll
    for (int off = 1; off <= 8; off <<= 1)
#pragma unroll
      for (int i = 0; i < 4; ++i)
        rs[i] += __shfl_xor(rs[i], off);
#pragma unroll
    for (int i = 0; i < 4; ++i) l_i[i] = l_i[i] * corr[i] + rs[i];
    if (!skip) {
#pragma unroll
      for (int df = 0; df < 4; ++df)
#pragma unroll
        for (int i = 0; i < 4; ++i) o[df][i] *= corr[i];
    }

    // ---- P -> LDS (bf16), then PV
#pragma unroll
    for (int nf = 0; nf < 8; ++nf)
#pragma unroll
      for (int i = 0; i < 4; ++i)
        pl[w][((l >> 4) * 4 + i) * 140 + nf * 16 + (l & 15)] = f2b_fast(sa[nf][i]);

    bf16x8 ap[4];
#pragma unroll
    for (int kf = 0; kf < 4; ++kf)
      ap[kf] = *(const bf16x8*)(&pl[w][(l & 15) * 140 + kf * 32 + (l >> 4) * 8]);
#pragma unroll
    for (int df = 0; df < 4; ++df) {
      const unsigned short* vp = &vt[(df * 16 + (l & 15)) * 136 + (l >> 4) * 8];
#pragma unroll
      for (int kf = 0; kf < 4; ++kf)
        o[df] = __builtin_amdgcn_mfma_f32_16x16x32_bf16(
            ap[kf], *(const bf16x8*)(vp + kf * 32), o[df], 0, 0, 0);
    }
  }
#undef PREFETCH

#pragma unroll
  for (int i = 0; i < 4; ++i) {
    int r = r0 + (l >> 4) * 4 + i;
    float inv = (r < slen && l_i[i] > 0.f) ? 1.0f / l_i[i] : 0.f;
#pragma unroll
    for (int df = 0; df < 4; ++df)
      att[((size_t)(b * 2048 + r)) * 1024 + h * 64 + df * 16 + (l & 15)] =
          f2b(o[df][i] * inv);
  }
}

// ----------------------------------------------------------- out GEMM -----
__global__ __launch_bounds__(256) void gemm_out(
    const unsigned short* __restrict__ A,    // att [4096][1024] bf16
    const unsigned short* __restrict__ Bt,   // WoT [1024][1024] bf16
    float* __restrict__ C) {
  const int K = 1024;
  __shared__ unsigned short lA[128 * 32];
  __shared__ unsigned short lB[128 * 32];
  int tid = threadIdx.x, l = tid & 63, w = tid >> 6;
  int wr = w >> 1, wc = w & 1;
  int m0 = blockIdx.x * 128;
  int n0 = blockIdx.y * 128;

  f32x4 acc[4][4] = {};

  const unsigned short* ga = A  + (size_t)(m0 + w*16 + (l >> 2)) * K + (l & 3) * 8;
  const unsigned short* gb = Bt + (size_t)(n0 + w*16 + (l >> 2)) * K + (l & 3) * 8;
  unsigned short* la0 = &lA[(w * 16) * 32];
  unsigned short* lb0 = &lB[(w * 16) * 32];

  for (int k0 = 0; k0 < K; k0 += 32) {
    gl_lds16(ga + k0,                  la0);
    gl_lds16(ga + (size_t)64 * K + k0, la0 + 64 * 32);
    gl_lds16(gb + k0,                  lb0);
    gl_lds16(gb + (size_t)64 * K + k0, lb0 + 64 * 32);
    __syncthreads();
    bf16x8 af[4], bfr[4];
#pragma unroll
    for (int mf = 0; mf < 4; ++mf)
      af[mf] = *(const bf16x8*)(&lA[(wr * 64 + mf * 16 + (l & 15)) * 32 + (l >> 4) * 8]);
#pragma unroll
    for (int nf = 0; nf < 4; ++nf)
      bfr[nf] = *(const bf16x8*)(&lB[(wc * 64 + nf * 16 + (l & 15)) * 32 + (l >> 4) * 8]);
#pragma unroll
    for (int mf = 0; mf < 4; ++mf)
#pragma unroll
      for (int nf = 0; nf < 4; ++nf)
        acc[mf][nf] = __builtin_amdgcn_mfma_f32_16x16x32_bf16(af[mf], bfr[nf], acc[mf][nf], 0, 0, 0);
    __syncthreads();
  }

  int colbase = n0 + wc * 64;
  int rowbase = m0 + wr * 64;
#pragma unroll
  for (int mf = 0; mf < 4; ++mf)
#pragma unroll
    for (int nf = 0; nf < 4; ++nf) {
      int n    = colbase + nf * 16 + (l & 15);
      int mrow = rowbase + mf * 16 + ((l >> 4) << 2);
#pragma unroll
      for (int i = 0; i < 4; ++i)
        C[(size_t)(mrow + i) * 1024 + n] = acc[mf][nf][i];
    }
}

// ---------------------------------------------------------------------------
extern "C" void kernel_launch(void* const* d_in, const int* in_sizes, int n_in,
                              void* d_out, int out_size, void* d_ws, size_t ws_size,
                              hipStream_t stream) {
  const float* x  = (const float*)d_in[0];
  const int*   sl = (const int*)d_in[1];
  const float* Wq = (const float*)d_in[2];
  const float* Wk = (const float*)d_in[3];
  const float* Wv = (const float*)d_in[4];
  const float* Wo = (const float*)d_in[5];
  float* out = (float*)d_out;

  char* p = (char*)d_ws;
  unsigned short* xb  = (unsigned short*)p; p += (size_t)4096 * 1024 * 2;
  unsigned short* wqT = (unsigned short*)p; p += (size_t)1024 * 1024 * 2;
  unsigned short* wkT = (unsigned short*)p; p += (size_t)256  * 1024 * 2;
  unsigned short* wvT = (unsigned short*)p; p += (size_t)256  * 1024 * 2;
  unsigned short* woT = (unsigned short*)p; p += (size_t)1024 * 1024 * 2;
  unsigned short* qb  = (unsigned short*)p; p += (size_t)B_ * H_   * T_ * D_ * 2;
  unsigned short* kbf = (unsigned short*)p; p += (size_t)B_ * HKV_ * T_ * D_ * 2;
  unsigned short* vbT = (unsigned short*)p; p += (size_t)B_ * HKV_ * D_ * T_ * 2;
  unsigned short* att = (unsigned short*)p; p += (size_t)4096 * 1024 * 2;

  cvt_kernel<<<4096, 256, 0, stream>>>(x, xb, 4096 * 1024 / 4);
  transpose_all<<<dim3(32, 32, 4), 256, 0, stream>>>(Wq, Wk, Wv, Wo, wqT, wkT, wvT, woT);
  gemm_qkv<<<dim3(32, 12), 256, 0, stream>>>(xb, wqT, wkT, wvT, qb, kbf, vbT);
  attn_kernel<<<1024, 256, 0, stream>>>(qb, kbf, vbT, sl, att);
  gemm_out<<<dim3(32, 8), 256, 0, stream>>>(att, woT, out);
}